// Round 7
// baseline (1849.949 us; speedup 1.0000x reference)
//
#include <hip/hip_runtime.h>
#include <math.h>

#define NN    64
#define NXX   4096
#define NT    1024
#define NW    16         // waves per block
#define NCH   4          // elements per thread = NXX/NT
#define NITER 25
#define EPSQ  0.1
#define SREG  1e-9
#define BIGV  1e10

// ---- wave (64-lane) reductions -------------------------------------------
__device__ __forceinline__ double wsum(double v) {
#pragma unroll
  for (int m = 32; m > 0; m >>= 1) v += __shfl_xor(v, m, 64);
  return v;
}
__device__ __forceinline__ double wmin(double v) {
#pragma unroll
  for (int m = 32; m > 0; m >>= 1) v = fmin(v, __shfl_xor(v, m, 64));
  return v;
}
__device__ __forceinline__ double wmax(double v) {
#pragma unroll
  for (int m = 32; m > 0; m >>= 1) v = fmax(v, __shfl_xor(v, m, 64));
  return v;
}

// 16x16 pivot-block inversion in one wave (registers + shfl), rcp+2NR divide.
#define F1_INVERT(K0)                                                         \
  {                                                                           \
    const int r_ = lane >> 2, q_ = lane & 3;                                  \
    double Brow[4];                                                           \
    _Pragma("unroll")                                                         \
    for (int e = 0; e < 4; ++e) Brow[e] = Mg[(K0) + r_][(K0) + ((e << 2) | q_)]; \
    _Pragma("unroll")                                                         \
    for (int t = 0; t < 16; ++t) {                                            \
      const int et = t >> 2, qt = t & 3;                                      \
      double pm  = __shfl(Brow[et], (r_ << 2) | qt, 64);                      \
      double pv  = __shfl(Brow[et], (t << 2) | qt, 64);                       \
      double pr0 = __shfl(Brow[0], (t << 2) | q_, 64);                        \
      double pr1 = __shfl(Brow[1], (t << 2) | q_, 64);                        \
      double pr2 = __shfl(Brow[2], (t << 2) | q_, 64);                        \
      double pr3 = __shfl(Brow[3], (t << 2) | q_, 64);                        \
      double ip = __builtin_amdgcn_rcp(pv);                                   \
      ip = ip * (2.0 - pv * ip);                                              \
      ip = ip * (2.0 - pv * ip);                                              \
      double ps0 = pr0 * ip, ps1 = pr1 * ip, ps2 = pr2 * ip, ps3 = pr3 * ip;  \
      if (r_ == t) {                                                          \
        Brow[0] = ps0; Brow[1] = ps1; Brow[2] = ps2; Brow[3] = ps3;           \
        if (q_ == qt) Brow[et] = ip;                                          \
      } else {                                                                \
        Brow[0] -= pm * ps0; Brow[1] -= pm * ps1;                             \
        Brow[2] -= pm * ps2; Brow[3] -= pm * ps3;                             \
        if (q_ == qt) Brow[et] = -pm * ip;                                    \
      }                                                                       \
    }                                                                         \
    _Pragma("unroll")                                                         \
    for (int e = 0; e < 4; ++e) Binv[r_][(e << 2) | q_] = Brow[e];            \
  }

// pair index -> (j,l), j>l, idx = j(j-1)/2 + l
__device__ __forceinline__ void pair_jl(int idx, int& j, int& l) {
  j = (int)((1.0 + sqrt(8.0 * (double)idx + 1.0)) * 0.5);
  while (j * (j - 1) / 2 > idx) --j;
  while ((j + 1) * j / 2 <= idx) ++j;
  l = idx - j * (j - 1) / 2;
}

// One block per batch element. 1024 threads = 16 waves, 4 waves/EU.
// Element e = tid + 1024*k (k=0..3). grid row i = w + 16k, col j = lane.
__global__ __launch_bounds__(NT, 4)
void ipm_kernel(const float* __restrict__ xin, const float* __restrict__ gidin,
                const float* __restrict__ expin, float* __restrict__ outp)
{
  const int b    = blockIdx.x;
  const int tid  = threadIdx.x;
  const int lane = tid & 63;
  const int w    = tid >> 6;     // wave id 0..15

  // ---- LDS ----------------------------------------------------------------
  __shared__ double DnT[64][65];     // DnT[j][i] = invD(i,j)/sqrt(Rh_i)
  __shared__ double Mg[64][67];      // augmented reduced Schur [M | rhs_d | mw]
  __shared__ double Pbuf[16][52];
  __shared__ double Binv[16][18];
  __shared__ double cpZ[NW][64], cpA[NW][64], cpB[NW][64], cpC[NW][64];
  __shared__ double req1[64];
  __shared__ double rhs1[64], rhs2v[64];
  __shared__ double Rhv[64], Ruv[64], ccv[64], wvv[64];
  __shared__ double usv[64], rsv[64], uvv[64], mw0[64];
  __shared__ double yav[64], ydv[64];
  __shared__ double fvec[64], evec[64];
  __shared__ double wpFz[NW], wpMu[NW], wpQ[NW], wpFg[NW], wpS[NW], wpL[NW];
  __shared__ double scal[8];  // 6=yt 7=gsum

  // ---- constants f, e; init y --------------------------------------------
  if (tid < 64) {
    fvec[tid] = (double)gidin[tid];   // reference uses group_ids[0] for ALL batches
    evec[tid] = (double)expin[tid];
    yav[tid] = 0.0; ydv[tid] = 0.0;
  }
  if (tid == 0) scal[6] = 0.0;
  __syncthreads();
  if (tid == 0) {
    double gs = 0.0;
    for (int i = 0; i < 64; ++i) gs += fvec[i];
    scal[7] = gs;
  }
  __syncthreads();
  if (tid < 64) {
    double g = fvec[tid], gs = scal[7];
    fvec[tid] = g / gs - (1.0 - g) / (64.0 - gs);
  }
  __syncthreads();

  // ---- per-thread state (40 persistent doubles incl. work arrays) --------
  double z[NCH], s1[NCH], s2[NCH], l1[NCH], l2[NCH];
  const double ev = evec[lane];
  const float* xb = xin + (size_t)b * NXX;
#pragma unroll
  for (int k = 0; k < NCH; ++k) {
    z[k] = 0.0; s1[k] = 1.0; s2[k] = 1.0; l1[k] = 1.0; l2[k] = 1.0;
  }

  // ======================= main IPM loop ==================================
  for (int iter = 0; iter < NITER; ++iter) {
    // ---- Phase A: row sums of z, fairness/mu partials --------------------
    double cz = 0.0, fz = 0.0, msl = 0.0;
#pragma unroll
    for (int k = 0; k < NCH; ++k) {
      int i = w + NW * k;
      double fek = fvec[i] * ev;
      double rsum = wsum(z[k]);
      if (lane == 0) req1[i] = rsum - 1.0;
      cz  += z[k];
      fz  += fek * z[k];
      msl += s1[k] * l1[k] + s2[k] * l2[k];
    }
    cpZ[w][lane] = cz;
    {
      double a = wsum(fz), c = wsum(msl);
      if (lane == 0) { wpFz[w] = a; wpMu[w] = c; }
    }
    __syncthreads();

    // ---- Phase C: invD, rhs_z, first-order reductions, DnT write ---------
    double mu8 = 0.0;
#pragma unroll
    for (int q = 0; q < NW; ++q) mu8 += wpMu[q];
    const double mu01 = 0.1 * (mu8 / 8192.0);
    const double yt   = scal[6];
    double dinv[NCH], rz[NCH], is1[NCH], is2[NCH];
    double cD = 0.0, cfD = 0.0, cg = 0.0, qac = 0.0, fgac = 0.0;
#pragma unroll
    for (int k = 0; k < NCH; ++k) {
      int i = w + NW * k;
      double fek = fvec[i] * ev;
      double pv  = (double)xb[tid + NT * k];
      is1[k] = 1.0 / s1[k];  is2[k] = 1.0 / s2[k];
      double D = 1.0 / (EPSQ + l1[k] * is1[k] + l2[k] * is2[k]);
      dinv[k] = D;
      double rd  = EPSQ * z[k] + pv + (yav[i] + ydv[lane] + yt * fek) + (l2[k] - l1[k]);
      double tt1 = (mu01 - l1[k] * z[k]) * is1[k];
      double tt2 = (l2[k] * (z[k] - 1.0) + mu01) * is2[k];
      double r = -(rd - tt1 + tt2);
      rz[k] = r;
      double g = r * D;
      double sD  = wsum(D);
      double sED = wsum(ev * D);
      double sg  = wsum(g);
      double Rh  = sD + SREG;
      if (lane == 0) {
        Rhv[i]  = Rh;
        Ruv[i]  = sED;
        rhs1[i] = sg + req1[i];
      }
      DnT[lane][i] = D * rsqrt(Rh);
      cD  += D;  cfD += fvec[i] * D;  cg += g;
      qac += fek * fek * D;
      fgac += fek * g;
    }
    cpA[w][lane] = cD; cpB[w][lane] = cfD; cpC[w][lane] = cg;
    {
      double a = wsum(qac), c = wsum(fgac);
      if (lane == 0) { wpQ[w] = a; wpFg[w] = c; }
    }
    __syncthreads();

    // ---- Phase D: column-sum finalize + border vectors -------------------
    if (tid < 64) {
      double sZ = 0.0, sA = 0.0, sB = 0.0, sC = 0.0;
#pragma unroll
      for (int q = 0; q < NW; ++q) {
        sZ += cpZ[q][tid]; sA += cpA[q][tid]; sB += cpB[q][tid]; sC += cpC[q][tid];
      }
      ccv[tid]   = sA;
      wvv[tid]   = evec[tid] * sB;
      rhs2v[tid] = sC + sZ - 1.0;
      double ir  = rsqrt(Rhv[tid]);
      double u   = fvec[tid] * Ruv[tid];
      uvv[tid] = u;
      usv[tid] = u * ir;
      rsv[tid] = rhs1[tid] * ir;
    }
    __syncthreads();

    // ---- Phase E: M upper part via 4x1 tiles (544 thr) + borders ---------
    // Tile (R,c): rows 4R..4R+3, col c (c >= 4R). Start(R) = 64R - 2R(R-1).
    if (tid < 544) {
      int R = 0;
#pragma unroll
      for (int r = 1; r < 16; ++r) if (tid >= (64 * r - 2 * r * (r - 1))) R = r;
      const int c  = 4 * R + (tid - (64 * R - 2 * R * (R - 1)));
      const int r0 = R << 2;
      double m0 = 0.0, m1 = 0.0, m2 = 0.0, m3 = 0.0;
#pragma unroll 8
      for (int i = 0; i < 64; ++i) {
        double bv = DnT[c][i];
        m0 += DnT[r0 + 0][i] * bv;
        m1 += DnT[r0 + 1][i] * bv;
        m2 += DnT[r0 + 2][i] * bv;
        m3 += DnT[r0 + 3][i] * bv;
      }
      Mg[r0 + 0][c] = ((r0 + 0) == c ? ccv[c] + SREG : 0.0) - m0;
      Mg[r0 + 1][c] = ((r0 + 1) == c ? ccv[c] + SREG : 0.0) - m1;
      Mg[r0 + 2][c] = ((r0 + 2) == c ? ccv[c] + SREG : 0.0) - m2;
      Mg[r0 + 3][c] = ((r0 + 3) == c ? ccv[c] + SREG : 0.0) - m3;
    } else if (tid < 672) {
      // border columns 64 (rhs_d) / 65 (mw): 128 serial dots of length 64
      const int d = tid - 544;
      const int j = d & 63, cc = d >> 6;
      double acc = 0.0;
#pragma unroll 8
      for (int i = 0; i < 64; ++i) {
        double vv = cc ? usv[i] : rsv[i];
        acc += DnT[j][i] * vv;
      }
      if (cc == 0) Mg[j][64] = rhs2v[j] - acc;
      else { double vv2 = wvv[j] - acc; Mg[j][65] = vv2; mw0[j] = vv2; }
    }
    __syncthreads();

    // ---- mirror lower triangle; wave 0 also inverts panel-0 pivot --------
    if (w == 0) {
#pragma unroll
      for (int e = 0; e < 2; ++e) {
        int idx = 2 * lane + e;
        if (idx < 120) { int j, l; pair_jl(idx, j, l); Mg[j][l] = Mg[l][j]; }
      }
      F1_INVERT(0);
    } else {
      const int wtid = tid - 64;     // 0..959
#pragma unroll
      for (int r = 0; r < 2; ++r) {
        int idx = 120 + wtid + 960 * r;
        if (idx < 2016) { int j, l; pair_jl(idx, j, l); Mg[j][l] = Mg[l][j]; }
      }
    }
    __syncthreads();

    // ---- Phase F: block Gauss-Jordan, 4 panels; F1(next) hidden in F3 ----
#pragma unroll
    for (int pk = 0; pk < 4; ++pk) {
      const int k0   = 16 * pk;
      const int rest = 50 - k0;        // 50, 34, 18, 2

      // -- F2: Pbuf = Binv * Mg[panel rows, rest cols] --------------------
      for (int o = tid; o < 16 * rest; o += NT) {
        int t = o / rest, c = o - t * rest;
        double acc = 0.0;
#pragma unroll
        for (int s = 0; s < 16; ++s) acc += Binv[t][s] * Mg[k0 + s][k0 + 16 + c];
        Pbuf[t][c] = acc;
      }
      __syncthreads();

      // -- F3 phase -------------------------------------------------------
      if (pk < 3) {
        if (w == 0) {
          // update next pivot block (16x16), then invert it
#pragma unroll
          for (int e = 0; e < 4; ++e) {
            int idx = lane + 64 * e;                 // 0..255
            int r = k0 + 16 + (idx >> 4), c = (idx & 15);
            double acc = Mg[r][k0 + 16 + c];
#pragma unroll
            for (int t = 0; t < 16; ++t) acc -= Mg[r][k0 + t] * Pbuf[t][c];
            Mg[r][k0 + 16 + c] = acc;
          }
          F1_INVERT(k0 + 16);
        } else {
          const int wtid = tid - 64;
          for (int o = wtid; o < 48 * rest; o += 960) {
            int rr = o / rest, c = o - rr * rest;
            int r = rr < k0 ? rr : rr + 16;
            bool excl = (r >= k0 + 16) && (r < k0 + 32) && (c < 16);
            if (!excl) {
              double acc = Mg[r][k0 + 16 + c];
#pragma unroll
              for (int t = 0; t < 16; ++t) acc -= Mg[r][k0 + t] * Pbuf[t][c];
              Mg[r][k0 + 16 + c] = acc;
            }
          }
          for (int o = wtid; o < 16 * rest; o += 960) {
            int t = o / rest, c = o - t * rest;
            Mg[k0 + t][k0 + 16 + c] = Pbuf[t][c];
          }
        }
      } else {
        // last panel: rest=2, tiny — all threads
        for (int o = tid; o < 48 * rest; o += NT) {
          int rr = o / rest, c = o - rr * rest;
          int r = rr < k0 ? rr : rr + 16;
          double acc = Mg[r][k0 + 16 + c];
#pragma unroll
          for (int t = 0; t < 16; ++t) acc -= Mg[r][k0 + t] * Pbuf[t][c];
          Mg[r][k0 + 16 + c] = acc;
        }
        for (int o = tid; o < 16 * rest; o += NT) {
          int t = o / rest, c = o - t * rest;
          Mg[k0 + t][k0 + 16 + c] = Pbuf[t][c];
        }
      }
      __syncthreads();
    }

    // ---- Phase H: fairness border solve (redundant in every wave) --------
    double ddl, tf;
    {
      double qsum = 0.0, fg = 0.0, fzs = 0.0;
#pragma unroll
      for (int q = 0; q < NW; ++q) { qsum += wpQ[q]; fg += wpFg[q]; fzs += wpFz[q]; }
      double h1 = Mg[lane][64], h2 = Mg[lane][65];
      double a1 = wsum(usv[lane] * usv[lane]);
      double a2 = wsum(usv[lane] * rsv[lane]);
      double a3 = wsum(mw0[lane] * h1);
      double a4 = wsum(mw0[lane] * h2);
      double qp  = qsum + SREG - a1;
      double r3p = (fg + fzs) - a2;
      tf  = (r3p - a3) / (qp - a4);
      ddl = h1 - tf * h2;
    }

    // ---- Phase I: row duals (in-register), dz/ds/dlam, alpha -------------
    double dar[NCH];
    double bs = 0.0;          // s-side rate max
    double rl = BIGV;         // lambda-side ratio min
#pragma unroll
    for (int k = 0; k < NCH; ++k) {
      int i = w + NW * k;
      double fek = fvec[i] * ev;
      double rdot = wsum(dinv[k] * ddl);
      double dv = (rhs1[i] - rdot - uvv[i] * tf) / Rhv[i];
      dar[k] = dv;
      double d   = (rz[k] - (dv + ddl + tf * fek)) * dinv[k];
      double ds1 = d - (s1[k] - z[k]);
      double ds2 = -(z[k] + s2[k] - 1.0) - d;
      bs = fmax(bs, fmax(-ds1 * is1[k], -ds2 * is2[k]));
      double dl1 = (-(l1[k] * s1[k] - mu01) - l1[k] * ds1) * is1[k];
      double dl2 = (-(l2[k] * s2[k] - mu01) - l2[k] * ds2) * is2[k];
      if (dl1 < 0.0) rl = fmin(rl, -l1[k] / dl1);
      if (dl2 < 0.0) rl = fmin(rl, -l2[k] / dl2);
    }
    bs = wmax(bs);
    rl = wmin(rl);
    if (lane == 0) { wpS[w] = bs; wpL[w] = rl; }
    __syncthreads();
    double al;
    {
      double bm = wpS[0], rm = wpL[0];
#pragma unroll
      for (int q = 1; q < NW; ++q) { bm = fmax(bm, wpS[q]); rm = fmin(rm, wpL[q]); }
      double a_s = bm > 0.0 ? 1.0 / bm : BIGV;
      al = fmin(1.0, 0.99 * fmin(a_s, rm));
    }

    // ---- update ----------------------------------------------------------
#pragma unroll
    for (int k = 0; k < NCH; ++k) {
      int i = w + NW * k;
      double fek = fvec[i] * ev;
      double d   = (rz[k] - (dar[k] + ddl + tf * fek)) * dinv[k];
      double ds1 = d - (s1[k] - z[k]);
      double ds2 = -(z[k] + s2[k] - 1.0) - d;
      double dl1 = (-(l1[k] * s1[k] - mu01) - l1[k] * ds1) * is1[k];
      double dl2 = (-(l2[k] * s2[k] - mu01) - l2[k] * ds2) * is2[k];
      z[k]  += al * d;
      s1[k] += al * ds1;
      s2[k] += al * ds2;
      l1[k] += al * dl1;
      l2[k] += al * dl2;
      if (lane == 0) yav[i] += al * dar[k];
    }
    if (tid < 64) ydv[tid] += al * ddl;
    if (tid == 0) scal[6] += al * tf;
    // no end barrier: Phase A's barrier orders these LDS writes before C's reads
  }

  // ---- output (fp32) ------------------------------------------------------
#pragma unroll
  for (int k = 0; k < NCH; ++k) {
    int e = tid + NT * k;
    outp[(size_t)b * NXX + e] = (float)z[k];
  }
}

extern "C" void kernel_launch(void* const* d_in, const int* in_sizes, int n_in,
                              void* d_out, int out_size, void* d_ws, size_t ws_size,
                              hipStream_t stream)
{
  const float* x   = (const float*)d_in[0];
  const float* gid = (const float*)d_in[1];
  const float* ex  = (const float*)d_in[2];
  float* out = (float*)d_out;
  int nb = in_sizes[0] / NXX;   // 32 batches
  hipLaunchKernelGGL(ipm_kernel, dim3(nb), dim3(NT), 0, stream, x, gid, ex, out);
}

// Round 9
// 1846.424 us; speedup vs baseline: 1.0019x; 1.0019x over previous
//
#include <hip/hip_runtime.h>
#include <math.h>

#define NN    64
#define NXX   4096
#define NT    1024
#define NW    16         // waves per block
#define NCH   4          // elements per thread = NXX/NT
#define NITER 25
#define EPSQ  0.1
#define SREG  1e-9
#define BIGV  1e10

// ---- wave (64-lane) reductions -------------------------------------------
__device__ __forceinline__ double wsum(double v) {
#pragma unroll
  for (int m = 32; m > 0; m >>= 1) v += __shfl_xor(v, m, 64);
  return v;
}
__device__ __forceinline__ double wmin(double v) {
#pragma unroll
  for (int m = 32; m > 0; m >>= 1) v = fmin(v, __shfl_xor(v, m, 64));
  return v;
}
__device__ __forceinline__ double wmax(double v) {
#pragma unroll
  for (int m = 32; m > 0; m >>= 1) v = fmax(v, __shfl_xor(v, m, 64));
  return v;
}

// 16x16 pivot-block inversion in one wave (registers + shfl), rcp+2NR divide.
#define F1_INVERT(K0)                                                         \
  {                                                                           \
    const int r_ = lane >> 2, q_ = lane & 3;                                  \
    double Brow[4];                                                           \
    _Pragma("unroll")                                                         \
    for (int e = 0; e < 4; ++e) Brow[e] = Mg[(K0) + r_][(K0) + ((e << 2) | q_)]; \
    _Pragma("unroll")                                                         \
    for (int t = 0; t < 16; ++t) {                                            \
      const int et = t >> 2, qt = t & 3;                                      \
      double pm  = __shfl(Brow[et], (r_ << 2) | qt, 64);                      \
      double pv  = __shfl(Brow[et], (t << 2) | qt, 64);                       \
      double pr0 = __shfl(Brow[0], (t << 2) | q_, 64);                        \
      double pr1 = __shfl(Brow[1], (t << 2) | q_, 64);                        \
      double pr2 = __shfl(Brow[2], (t << 2) | q_, 64);                        \
      double pr3 = __shfl(Brow[3], (t << 2) | q_, 64);                        \
      double ip = __builtin_amdgcn_rcp(pv);                                   \
      ip = ip * (2.0 - pv * ip);                                              \
      ip = ip * (2.0 - pv * ip);                                              \
      double ps0 = pr0 * ip, ps1 = pr1 * ip, ps2 = pr2 * ip, ps3 = pr3 * ip;  \
      if (r_ == t) {                                                          \
        Brow[0] = ps0; Brow[1] = ps1; Brow[2] = ps2; Brow[3] = ps3;           \
        if (q_ == qt) Brow[et] = ip;                                          \
      } else {                                                                \
        Brow[0] -= pm * ps0; Brow[1] -= pm * ps1;                             \
        Brow[2] -= pm * ps2; Brow[3] -= pm * ps3;                             \
        if (q_ == qt) Brow[et] = -pm * ip;                                    \
      }                                                                       \
    }                                                                         \
    _Pragma("unroll")                                                         \
    for (int e = 0; e < 4; ++e) Binv[r_][(e << 2) | q_] = Brow[e];            \
  }

// pair index -> (j,l), j>l, idx = j(j-1)/2 + l
__device__ __forceinline__ void pair_jl(int idx, int& j, int& l) {
  j = (int)((1.0 + sqrt(8.0 * (double)idx + 1.0)) * 0.5);
  while (j * (j - 1) / 2 > idx) --j;
  while ((j + 1) * j / 2 <= idx) ++j;
  l = idx - j * (j - 1) / 2;
}

// One block per batch element. 1024 threads = 16 waves, exactly 4 waves/EU.
// LDS (118 KB) caps at 1 block/CU; tell the register allocator so (4,4).
__global__ __attribute__((amdgpu_flat_work_group_size(1024, 1024),
                          amdgpu_waves_per_eu(4, 4)))
void ipm_kernel(const float* __restrict__ xin, const float* __restrict__ gidin,
                const float* __restrict__ expin, float* __restrict__ outp)
{
  const int b    = blockIdx.x;
  const int tid  = threadIdx.x;
  const int lane = tid & 63;
  const int w    = tid >> 6;     // wave id 0..15

  // ---- LDS ----------------------------------------------------------------
  __shared__ double DnT[64][65];     // DnT[j][i] = invD(i,j)/sqrt(Rh_i)
  __shared__ double Mg[64][67];      // augmented reduced Schur [M | rhs_d | mw]
  __shared__ double Pbuf[16][52];
  __shared__ double Binv[16][18];
  __shared__ double cpZ[NW][64], cpA[NW][64], cpB[NW][64], cpC[NW][64];
  __shared__ double req1[64];
  __shared__ double rhs1[64], rhs2v[64];
  __shared__ double Rhv[64], Ruv[64], ccv[64], wvv[64];
  __shared__ double usv[64], rsv[64], uvv[64], mw0[64];
  __shared__ double yav[64], ydv[64];
  __shared__ double fvec[64], evec[64];
  __shared__ double wpFz[NW], wpMu[NW], wpQ[NW], wpFg[NW], wpS[NW], wpL[NW];
  __shared__ double scal[8];  // 6=yt 7=gsum

  // ---- constants f, e; init y --------------------------------------------
  if (tid < 64) {
    fvec[tid] = (double)gidin[tid];   // reference uses group_ids[0] for ALL batches
    evec[tid] = (double)expin[tid];
    yav[tid] = 0.0; ydv[tid] = 0.0;
  }
  if (tid == 0) scal[6] = 0.0;
  __syncthreads();
  if (tid == 0) {
    double gs = 0.0;
    for (int i = 0; i < 64; ++i) gs += fvec[i];
    scal[7] = gs;
  }
  __syncthreads();
  if (tid < 64) {
    double g = fvec[tid], gs = scal[7];
    fvec[tid] = g / gs - (1.0 - g) / (64.0 - gs);
  }
  __syncthreads();

  // ---- per-thread state (40 persistent doubles incl. work arrays) --------
  double z[NCH], s1[NCH], s2[NCH], l1[NCH], l2[NCH];
  const double ev = evec[lane];
  const float* xb = xin + (size_t)b * NXX;
#pragma unroll
  for (int k = 0; k < NCH; ++k) {
    z[k] = 0.0; s1[k] = 1.0; s2[k] = 1.0; l1[k] = 1.0; l2[k] = 1.0;
  }

  // ======================= main IPM loop ==================================
  for (int iter = 0; iter < NITER; ++iter) {
    // ---- Phase A: row sums of z, fairness/mu partials --------------------
    double cz = 0.0, fz = 0.0, msl = 0.0;
#pragma unroll
    for (int k = 0; k < NCH; ++k) {
      int i = w + NW * k;
      double fek = fvec[i] * ev;
      double rsum = wsum(z[k]);
      if (lane == 0) req1[i] = rsum - 1.0;
      cz  += z[k];
      fz  += fek * z[k];
      msl += s1[k] * l1[k] + s2[k] * l2[k];
    }
    cpZ[w][lane] = cz;
    {
      double a = wsum(fz), c = wsum(msl);
      if (lane == 0) { wpFz[w] = a; wpMu[w] = c; }
    }
    __syncthreads();

    // ---- Phase C: invD, rhs_z, first-order reductions, DnT write ---------
    double mu8 = 0.0;
#pragma unroll
    for (int q = 0; q < NW; ++q) mu8 += wpMu[q];
    const double mu01 = 0.1 * (mu8 / 8192.0);
    const double yt   = scal[6];
    double dinv[NCH], rz[NCH], is1[NCH], is2[NCH];
    double cD = 0.0, cfD = 0.0, cg = 0.0, qac = 0.0, fgac = 0.0;
#pragma unroll
    for (int k = 0; k < NCH; ++k) {
      int i = w + NW * k;
      double fek = fvec[i] * ev;
      double pv  = (double)xb[tid + NT * k];
      is1[k] = 1.0 / s1[k];  is2[k] = 1.0 / s2[k];
      double D = 1.0 / (EPSQ + l1[k] * is1[k] + l2[k] * is2[k]);
      dinv[k] = D;
      double rd  = EPSQ * z[k] + pv + (yav[i] + ydv[lane] + yt * fek) + (l2[k] - l1[k]);
      double tt1 = (mu01 - l1[k] * z[k]) * is1[k];
      double tt2 = (l2[k] * (z[k] - 1.0) + mu01) * is2[k];
      double r = -(rd - tt1 + tt2);
      rz[k] = r;
      double g = r * D;
      double sD  = wsum(D);
      double sED = wsum(ev * D);
      double sg  = wsum(g);
      double Rh  = sD + SREG;
      if (lane == 0) {
        Rhv[i]  = Rh;
        Ruv[i]  = sED;
        rhs1[i] = sg + req1[i];
      }
      DnT[lane][i] = D * rsqrt(Rh);
      cD  += D;  cfD += fvec[i] * D;  cg += g;
      qac += fek * fek * D;
      fgac += fek * g;
    }
    cpA[w][lane] = cD; cpB[w][lane] = cfD; cpC[w][lane] = cg;
    {
      double a = wsum(qac), c = wsum(fgac);
      if (lane == 0) { wpQ[w] = a; wpFg[w] = c; }
    }
    __syncthreads();

    // ---- Phase D: column-sum finalize + border vectors -------------------
    if (tid < 64) {
      double sZ = 0.0, sA = 0.0, sB = 0.0, sC = 0.0;
#pragma unroll
      for (int q = 0; q < NW; ++q) {
        sZ += cpZ[q][tid]; sA += cpA[q][tid]; sB += cpB[q][tid]; sC += cpC[q][tid];
      }
      ccv[tid]   = sA;
      wvv[tid]   = evec[tid] * sB;
      rhs2v[tid] = sC + sZ - 1.0;
      double ir  = rsqrt(Rhv[tid]);
      double u   = fvec[tid] * Ruv[tid];
      uvv[tid] = u;
      usv[tid] = u * ir;
      rsv[tid] = rhs1[tid] * ir;
    }
    __syncthreads();

    // ---- Phase E: M upper part via 4x1 tiles (544 thr) + borders ---------
    // Tile (R,c): rows 4R..4R+3, col c (c >= 4R). Start(R) = 64R - 2R(R-1).
    if (tid < 544) {
      int R = 0;
#pragma unroll
      for (int r = 1; r < 16; ++r) if (tid >= (64 * r - 2 * r * (r - 1))) R = r;
      const int c  = 4 * R + (tid - (64 * R - 2 * R * (R - 1)));
      const int r0 = R << 2;
      double m0 = 0.0, m1 = 0.0, m2 = 0.0, m3 = 0.0;
#pragma unroll 8
      for (int i = 0; i < 64; ++i) {
        double bv = DnT[c][i];
        m0 += DnT[r0 + 0][i] * bv;
        m1 += DnT[r0 + 1][i] * bv;
        m2 += DnT[r0 + 2][i] * bv;
        m3 += DnT[r0 + 3][i] * bv;
      }
      Mg[r0 + 0][c] = ((r0 + 0) == c ? ccv[c] + SREG : 0.0) - m0;
      Mg[r0 + 1][c] = ((r0 + 1) == c ? ccv[c] + SREG : 0.0) - m1;
      Mg[r0 + 2][c] = ((r0 + 2) == c ? ccv[c] + SREG : 0.0) - m2;
      Mg[r0 + 3][c] = ((r0 + 3) == c ? ccv[c] + SREG : 0.0) - m3;
    } else if (tid < 672) {
      // border columns 64 (rhs_d) / 65 (mw): 128 serial dots of length 64
      const int d = tid - 544;
      const int j = d & 63, cc = d >> 6;
      double acc = 0.0;
#pragma unroll 8
      for (int i = 0; i < 64; ++i) {
        double vv = cc ? usv[i] : rsv[i];
        acc += DnT[j][i] * vv;
      }
      if (cc == 0) Mg[j][64] = rhs2v[j] - acc;
      else { double vv2 = wvv[j] - acc; Mg[j][65] = vv2; mw0[j] = vv2; }
    }
    __syncthreads();

    // ---- mirror lower triangle; wave 0 also inverts panel-0 pivot --------
    if (w == 0) {
#pragma unroll
      for (int e = 0; e < 2; ++e) {
        int idx = 2 * lane + e;
        if (idx < 120) { int j, l; pair_jl(idx, j, l); Mg[j][l] = Mg[l][j]; }
      }
      F1_INVERT(0);
    } else {
      const int wtid = tid - 64;     // 0..959
#pragma unroll
      for (int r = 0; r < 2; ++r) {
        int idx = 120 + wtid + 960 * r;
        if (idx < 2016) { int j, l; pair_jl(idx, j, l); Mg[j][l] = Mg[l][j]; }
      }
    }
    __syncthreads();

    // ---- Phase F: block Gauss-Jordan, 4 panels; F1(next) hidden in F3 ----
#pragma unroll
    for (int pk = 0; pk < 4; ++pk) {
      const int k0   = 16 * pk;
      const int rest = 50 - k0;        // 50, 34, 18, 2

      // -- F2: Pbuf = Binv * Mg[panel rows, rest cols] --------------------
      for (int o = tid; o < 16 * rest; o += NT) {
        int t = o / rest, c = o - t * rest;
        double acc = 0.0;
#pragma unroll
        for (int s = 0; s < 16; ++s) acc += Binv[t][s] * Mg[k0 + s][k0 + 16 + c];
        Pbuf[t][c] = acc;
      }
      __syncthreads();

      // -- F3 phase -------------------------------------------------------
      if (pk < 3) {
        if (w == 0) {
          // update next pivot block (16x16), then invert it
#pragma unroll
          for (int e = 0; e < 4; ++e) {
            int idx = lane + 64 * e;                 // 0..255
            int r = k0 + 16 + (idx >> 4), c = (idx & 15);
            double acc = Mg[r][k0 + 16 + c];
#pragma unroll
            for (int t = 0; t < 16; ++t) acc -= Mg[r][k0 + t] * Pbuf[t][c];
            Mg[r][k0 + 16 + c] = acc;
          }
          F1_INVERT(k0 + 16);
        } else {
          const int wtid = tid - 64;
          for (int o = wtid; o < 48 * rest; o += 960) {
            int rr = o / rest, c = o - rr * rest;
            int r = rr < k0 ? rr : rr + 16;
            bool excl = (r >= k0 + 16) && (r < k0 + 32) && (c < 16);
            if (!excl) {
              double acc = Mg[r][k0 + 16 + c];
#pragma unroll
              for (int t = 0; t < 16; ++t) acc -= Mg[r][k0 + t] * Pbuf[t][c];
              Mg[r][k0 + 16 + c] = acc;
            }
          }
          for (int o = wtid; o < 16 * rest; o += 960) {
            int t = o / rest, c = o - t * rest;
            Mg[k0 + t][k0 + 16 + c] = Pbuf[t][c];
          }
        }
      } else {
        // last panel: rest=2, tiny — all threads
        for (int o = tid; o < 48 * rest; o += NT) {
          int rr = o / rest, c = o - rr * rest;
          int r = rr < k0 ? rr : rr + 16;
          double acc = Mg[r][k0 + 16 + c];
#pragma unroll
          for (int t = 0; t < 16; ++t) acc -= Mg[r][k0 + t] * Pbuf[t][c];
          Mg[r][k0 + 16 + c] = acc;
        }
        for (int o = tid; o < 16 * rest; o += NT) {
          int t = o / rest, c = o - t * rest;
          Mg[k0 + t][k0 + 16 + c] = Pbuf[t][c];
        }
      }
      __syncthreads();
    }

    // ---- Phase H: fairness border solve (redundant in every wave) --------
    double ddl, tf;
    {
      double qsum = 0.0, fg = 0.0, fzs = 0.0;
#pragma unroll
      for (int q = 0; q < NW; ++q) { qsum += wpQ[q]; fg += wpFg[q]; fzs += wpFz[q]; }
      double h1 = Mg[lane][64], h2 = Mg[lane][65];
      double a1 = wsum(usv[lane] * usv[lane]);
      double a2 = wsum(usv[lane] * rsv[lane]);
      double a3 = wsum(mw0[lane] * h1);
      double a4 = wsum(mw0[lane] * h2);
      double qp  = qsum + SREG - a1;
      double r3p = (fg + fzs) - a2;
      tf  = (r3p - a3) / (qp - a4);
      ddl = h1 - tf * h2;
    }

    // ---- Phase I: row duals (in-register), dz/ds/dlam, alpha -------------
    double dar[NCH];
    double bs = 0.0;          // s-side rate max
    double rl = BIGV;         // lambda-side ratio min
#pragma unroll
    for (int k = 0; k < NCH; ++k) {
      int i = w + NW * k;
      double fek = fvec[i] * ev;
      double rdot = wsum(dinv[k] * ddl);
      double dv = (rhs1[i] - rdot - uvv[i] * tf) / Rhv[i];
      dar[k] = dv;
      double d   = (rz[k] - (dv + ddl + tf * fek)) * dinv[k];
      double ds1 = d - (s1[k] - z[k]);
      double ds2 = -(z[k] + s2[k] - 1.0) - d;
      bs = fmax(bs, fmax(-ds1 * is1[k], -ds2 * is2[k]));
      double dl1 = (-(l1[k] * s1[k] - mu01) - l1[k] * ds1) * is1[k];
      double dl2 = (-(l2[k] * s2[k] - mu01) - l2[k] * ds2) * is2[k];
      if (dl1 < 0.0) rl = fmin(rl, -l1[k] / dl1);
      if (dl2 < 0.0) rl = fmin(rl, -l2[k] / dl2);
    }
    bs = wmax(bs);
    rl = wmin(rl);
    if (lane == 0) { wpS[w] = bs; wpL[w] = rl; }
    __syncthreads();
    double al;
    {
      double bm = wpS[0], rm = wpL[0];
#pragma unroll
      for (int q = 1; q < NW; ++q) { bm = fmax(bm, wpS[q]); rm = fmin(rm, wpL[q]); }
      double a_s = bm > 0.0 ? 1.0 / bm : BIGV;
      al = fmin(1.0, 0.99 * fmin(a_s, rm));
    }

    // ---- update ----------------------------------------------------------
#pragma unroll
    for (int k = 0; k < NCH; ++k) {
      int i = w + NW * k;
      double fek = fvec[i] * ev;
      double d   = (rz[k] - (dar[k] + ddl + tf * fek)) * dinv[k];
      double ds1 = d - (s1[k] - z[k]);
      double ds2 = -(z[k] + s2[k] - 1.0) - d;
      double dl1 = (-(l1[k] * s1[k] - mu01) - l1[k] * ds1) * is1[k];
      double dl2 = (-(l2[k] * s2[k] - mu01) - l2[k] * ds2) * is2[k];
      z[k]  += al * d;
      s1[k] += al * ds1;
      s2[k] += al * ds2;
      l1[k] += al * dl1;
      l2[k] += al * dl2;
      if (lane == 0) yav[i] += al * dar[k];
    }
    if (tid < 64) ydv[tid] += al * ddl;
    if (tid == 0) scal[6] += al * tf;
    // no end barrier: Phase A's barrier orders these LDS writes before C's reads
  }

  // ---- output (fp32) ------------------------------------------------------
#pragma unroll
  for (int k = 0; k < NCH; ++k) {
    int e = tid + NT * k;
    outp[(size_t)b * NXX + e] = (float)z[k];
  }
}

extern "C" void kernel_launch(void* const* d_in, const int* in_sizes, int n_in,
                              void* d_out, int out_size, void* d_ws, size_t ws_size,
                              hipStream_t stream)
{
  const float* x   = (const float*)d_in[0];
  const float* gid = (const float*)d_in[1];
  const float* ex  = (const float*)d_in[2];
  float* out = (float*)d_out;
  int nb = in_sizes[0] / NXX;   // 32 batches
  hipLaunchKernelGGL(ipm_kernel, dim3(nb), dim3(NT), 0, stream, x, gid, ex, out);
}

// Round 11
// 1370.774 us; speedup vs baseline: 1.3496x; 1.3470x over previous
//
#include <hip/hip_runtime.h>
#include <math.h>

#define NN    64
#define NXX   4096
#define NT    512
#define NW    8          // waves per block
#define NCH   8          // elements per thread = NXX/NT
#define NITER 25
#define EPSQ  0.1
#define SREG  1e-9
#define BIGV  1e10

// ---- wave (64-lane) reductions -------------------------------------------
__device__ __forceinline__ double wsum(double v) {
#pragma unroll
  for (int m = 32; m > 0; m >>= 1) v += __shfl_xor(v, m, 64);
  return v;
}
__device__ __forceinline__ double wmin(double v) {
#pragma unroll
  for (int m = 32; m > 0; m >>= 1) v = fmin(v, __shfl_xor(v, m, 64));
  return v;
}
__device__ __forceinline__ double wmax(double v) {
#pragma unroll
  for (int m = 32; m > 0; m >>= 1) v = fmax(v, __shfl_xor(v, m, 64));
  return v;
}

// 16x16 pivot-block inversion in one wave (registers + shfl), rcp+2NR divide.
#define F1_INVERT(K0)                                                         \
  {                                                                           \
    const int r_ = lane >> 2, q_ = lane & 3;                                  \
    double Brow[4];                                                           \
    _Pragma("unroll")                                                         \
    for (int e = 0; e < 4; ++e) Brow[e] = Mg[(K0) + r_][(K0) + ((e << 2) | q_)]; \
    _Pragma("unroll")                                                         \
    for (int t = 0; t < 16; ++t) {                                            \
      const int et = t >> 2, qt = t & 3;                                      \
      double pm  = __shfl(Brow[et], (r_ << 2) | qt, 64);                      \
      double pv  = __shfl(Brow[et], (t << 2) | qt, 64);                       \
      double pr0 = __shfl(Brow[0], (t << 2) | q_, 64);                        \
      double pr1 = __shfl(Brow[1], (t << 2) | q_, 64);                        \
      double pr2 = __shfl(Brow[2], (t << 2) | q_, 64);                        \
      double pr3 = __shfl(Brow[3], (t << 2) | q_, 64);                        \
      double ip = __builtin_amdgcn_rcp(pv);                                   \
      ip = ip * (2.0 - pv * ip);                                              \
      ip = ip * (2.0 - pv * ip);                                              \
      double ps0 = pr0 * ip, ps1 = pr1 * ip, ps2 = pr2 * ip, ps3 = pr3 * ip;  \
      if (r_ == t) {                                                          \
        Brow[0] = ps0; Brow[1] = ps1; Brow[2] = ps2; Brow[3] = ps3;           \
        if (q_ == qt) Brow[et] = ip;                                          \
      } else {                                                                \
        Brow[0] -= pm * ps0; Brow[1] -= pm * ps1;                             \
        Brow[2] -= pm * ps2; Brow[3] -= pm * ps3;                             \
        if (q_ == qt) Brow[et] = -pm * ip;                                    \
      }                                                                       \
    }                                                                         \
    _Pragma("unroll")                                                         \
    for (int e = 0; e < 4; ++e) Binv[r_][(e << 2) | q_] = Brow[e];            \
  }

// pair index -> (j,l), j>l, idx = j(j-1)/2 + l
__device__ __forceinline__ void pair_jl(int idx, int& j, int& l) {
  j = (int)((1.0 + sqrt(8.0 * (double)idx + 1.0)) * 0.5);
  while (j * (j - 1) / 2 > idx) --j;
  while ((j + 1) * j / 2 <= idx) ++j;
  l = idx - j * (j - 1) / 2;
}

// One block per batch element. 512 threads = 8 waves, 2 waves/EU (LDS-capped
// to 1 block/CU). amdgpu_num_vgpr(256): 2 waves/SIMD x 256 = full VGPR file,
// zero occupancy cost, kills spills if honored.
__global__ __attribute__((amdgpu_flat_work_group_size(NT, NT),
                          amdgpu_num_vgpr(256)))
void ipm_kernel(const float* __restrict__ xin, const float* __restrict__ gidin,
                const float* __restrict__ expin, float* __restrict__ outp)
{
  const int b    = blockIdx.x;
  const int tid  = threadIdx.x;
  const int lane = tid & 63;
  const int w    = tid >> 6;     // wave id 0..7

  // ---- LDS ----------------------------------------------------------------
  __shared__ double DnT[64][65];     // DnT[j][i] = invD(i,j)/sqrt(Rh_i)
  __shared__ double Mg[64][67];      // augmented reduced Schur [M | rhs_d | mw]
  __shared__ double Pbuf[16][52];
  __shared__ double Binv[16][18];
  __shared__ double cpZ[NW][64], cpA[NW][64], cpB[NW][64], cpC[NW][64];
  __shared__ double dzS[NCH][NT];    // Newton dz (written I, read update)
  __shared__ double req1[64], dav[64];
  __shared__ double rhs1[64], rhs2v[64];
  __shared__ double Rhv[64], Ruv[64], ccv[64], wvv[64];
  __shared__ double usv[64], rsv[64], uvv[64], mw0[64];
  __shared__ double yav[64], ydv[64];
  __shared__ double fvec[64], evec[64];
  __shared__ double wpFz[NW], wpMu[NW], wpQ[NW], wpFg[NW], wpS[NW], wpL[NW];
  __shared__ double scal[8];  // 6=yt 7=gsum

  // ---- constants f, e; init y --------------------------------------------
  if (tid < 64) {
    fvec[tid] = (double)gidin[tid];   // reference uses group_ids[0] for ALL batches
    evec[tid] = (double)expin[tid];
    yav[tid] = 0.0; ydv[tid] = 0.0;
  }
  if (tid == 0) scal[6] = 0.0;
  __syncthreads();
  if (tid == 0) {
    double gs = 0.0;
    for (int i = 0; i < 64; ++i) gs += fvec[i];
    scal[7] = gs;
  }
  __syncthreads();
  if (tid < 64) {
    double g = fvec[tid], gs = scal[7];
    fvec[tid] = g / gs - (1.0 - g) / (64.0 - gs);
  }
  __syncthreads();

  // ---- per-thread persistent state: 48 doubles = 96 VGPR ------------------
  double p[NCH], z[NCH], s1[NCH], s2[NCH], l1[NCH], l2[NCH];
  const double ev = evec[lane];
#pragma unroll
  for (int k = 0; k < NCH; ++k) {
    p[k] = (double)xin[(size_t)b * NXX + tid + NT * k];
    z[k] = 0.0; s1[k] = 1.0; s2[k] = 1.0; l1[k] = 1.0; l2[k] = 1.0;
  }

  // ======================= main IPM loop ==================================
  for (int iter = 0; iter < NITER; ++iter) {
    // ---- Phase A: row sums of z, fairness/mu partials --------------------
    double cz = 0.0, fz = 0.0, msl = 0.0;
#pragma unroll
    for (int k = 0; k < NCH; ++k) {
      int i = w + NW * k;
      double fek = fvec[i] * ev;
      double rsum = wsum(z[k]);
      if (lane == 0) req1[i] = rsum - 1.0;
      cz  += z[k];
      fz  += fek * z[k];
      msl += s1[k] * l1[k] + s2[k] * l2[k];
    }
    cpZ[w][lane] = cz;
    {
      double a = wsum(fz), c = wsum(msl);
      if (lane == 0) { wpFz[w] = a; wpMu[w] = c; }
    }
    __syncthreads();

    // ---- Phase C: invD, rhs_z, first-order reductions, DnT write ---------
    double mu8 = 0.0;
#pragma unroll
    for (int q = 0; q < NW; ++q) mu8 += wpMu[q];
    const double mu01 = 0.1 * (mu8 / 8192.0);
    const double yt   = scal[6];
    double cD = 0.0, cfD = 0.0, cg = 0.0, qac = 0.0, fgac = 0.0;
#pragma unroll
    for (int k = 0; k < NCH; ++k) {
      int i = w + NW * k;
      double fek = fvec[i] * ev;
      double is1 = 1.0 / s1[k], is2 = 1.0 / s2[k];
      double D = 1.0 / (EPSQ + l1[k] * is1 + l2[k] * is2);
      double rd  = EPSQ * z[k] + p[k] + (yav[i] + ydv[lane] + yt * fek) + (l2[k] - l1[k]);
      double tt1 = (mu01 - l1[k] * z[k]) * is1;
      double tt2 = (l2[k] * (z[k] - 1.0) + mu01) * is2;
      double r = -(rd - tt1 + tt2);
      double g = r * D;
      double sD  = wsum(D);
      double sED = wsum(ev * D);
      double sg  = wsum(g);
      double Rh  = sD + SREG;
      if (lane == 0) {
        Rhv[i]  = Rh;
        Ruv[i]  = sED;
        rhs1[i] = sg + req1[i];
      }
      DnT[lane][i] = D * rsqrt(Rh);
      cD  += D;  cfD += fvec[i] * D;  cg += g;
      qac += fek * fek * D;
      fgac += fek * g;
    }
    cpA[w][lane] = cD; cpB[w][lane] = cfD; cpC[w][lane] = cg;
    {
      double a = wsum(qac), c = wsum(fgac);
      if (lane == 0) { wpQ[w] = a; wpFg[w] = c; }
    }
    __syncthreads();

    // ---- Phase D: column-sum finalize + border vectors -------------------
    if (tid < 64) {
      double sZ = 0.0, sA = 0.0, sB = 0.0, sC = 0.0;
#pragma unroll
      for (int q = 0; q < NW; ++q) {
        sZ += cpZ[q][tid]; sA += cpA[q][tid]; sB += cpB[q][tid]; sC += cpC[q][tid];
      }
      ccv[tid]   = sA;
      wvv[tid]   = evec[tid] * sB;
      rhs2v[tid] = sC + sZ - 1.0;
      double ir  = rsqrt(Rhv[tid]);
      double u   = fvec[tid] * Ruv[tid];
      uvv[tid] = u;
      usv[tid] = u * ir;
      rsv[tid] = rhs1[tid] * ir;
    }
    __syncthreads();

    // ---- Phase E-main: upper-triangle 4x2 tiles (272 thr) + borders ------
    if (tid < 272) {
      int R = 0;
#pragma unroll
      for (int r = 1; r < 16; ++r) if (tid >= r * (33 - r)) R = r;
      const int C  = 2 * R + (tid - R * (33 - R));
      const int r0 = R << 2, c0 = C << 1;
      double m00=0.0,m01=0.0,m10=0.0,m11=0.0,m20=0.0,m21=0.0,m30=0.0,m31=0.0;
#pragma unroll 4
      for (int i = 0; i < 64; ++i) {
        double a0 = DnT[r0+0][i], a1 = DnT[r0+1][i];
        double a2 = DnT[r0+2][i], a3 = DnT[r0+3][i];
        double b0v = DnT[c0+0][i], b1v = DnT[c0+1][i];
        m00 += a0*b0v; m01 += a0*b1v;
        m10 += a1*b0v; m11 += a1*b1v;
        m20 += a2*b0v; m21 += a2*b1v;
        m30 += a3*b0v; m31 += a3*b1v;
      }
      Mg[r0+0][c0+0] = ((r0+0)==(c0+0) ? ccv[r0+0]+SREG : 0.0) - m00;
      Mg[r0+0][c0+1] = ((r0+0)==(c0+1) ? ccv[r0+0]+SREG : 0.0) - m01;
      Mg[r0+1][c0+0] = ((r0+1)==(c0+0) ? ccv[r0+1]+SREG : 0.0) - m10;
      Mg[r0+1][c0+1] = ((r0+1)==(c0+1) ? ccv[r0+1]+SREG : 0.0) - m11;
      Mg[r0+2][c0+0] = ((r0+2)==(c0+0) ? ccv[r0+2]+SREG : 0.0) - m20;
      Mg[r0+2][c0+1] = ((r0+2)==(c0+1) ? ccv[r0+2]+SREG : 0.0) - m21;
      Mg[r0+3][c0+0] = ((r0+3)==(c0+0) ? ccv[r0+3]+SREG : 0.0) - m30;
      Mg[r0+3][c0+1] = ((r0+3)==(c0+1) ? ccv[r0+3]+SREG : 0.0) - m31;
    } else if (tid < 400) {
      // border columns 64 (rhs_d) / 65 (mw): 128 serial dots of length 64
      const int d = tid - 272;
      const int j = d & 63, cc = d >> 6;
      double acc = 0.0;
#pragma unroll 8
      for (int i = 0; i < 64; ++i) {
        double vv = cc ? usv[i] : rsv[i];
        acc += DnT[j][i] * vv;
      }
      if (cc == 0) Mg[j][64] = rhs2v[j] - acc;
      else { double vv2 = wvv[j] - acc; Mg[j][65] = vv2; mw0[j] = vv2; }
    }
    __syncthreads();

    // ---- mirror lower triangle; wave 0 also inverts panel-0 pivot --------
    if (w == 0) {
#pragma unroll
      for (int e = 0; e < 2; ++e) {
        int idx = 2 * lane + e;
        if (idx < 120) { int j, l; pair_jl(idx, j, l); Mg[j][l] = Mg[l][j]; }
      }
      F1_INVERT(0);
    } else {
      const int wtid = tid - 64;
#pragma unroll
      for (int r = 0; r < 5; ++r) {
        int idx = 120 + wtid + 448 * r;
        if (idx < 2016) { int j, l; pair_jl(idx, j, l); Mg[j][l] = Mg[l][j]; }
      }
    }
    __syncthreads();

    // ---- Phase F: block Gauss-Jordan, 4 panels; F1(next) hidden in F3 ----
#pragma unroll
    for (int pk = 0; pk < 4; ++pk) {
      const int k0   = 16 * pk;
      const int rest = 50 - k0;        // 50, 34, 18, 2

      // -- F2: Pbuf = Binv * Mg[panel rows, rest cols] --------------------
      for (int o = tid; o < 16 * rest; o += NT) {
        int t = o / rest, c = o - t * rest;
        double acc = 0.0;
#pragma unroll
        for (int s = 0; s < 16; ++s) acc += Binv[t][s] * Mg[k0 + s][k0 + 16 + c];
        Pbuf[t][c] = acc;
      }
      __syncthreads();

      // -- F3 phase -------------------------------------------------------
      if (pk < 3) {
        if (w == 0) {
          // update next pivot block (16x16), then invert it
#pragma unroll
          for (int e = 0; e < 4; ++e) {
            int idx = lane + 64 * e;                 // 0..255
            int r = k0 + 16 + (idx >> 4), c = (idx & 15);
            double acc = Mg[r][k0 + 16 + c];
#pragma unroll
            for (int t = 0; t < 16; ++t) acc -= Mg[r][k0 + t] * Pbuf[t][c];
            Mg[r][k0 + 16 + c] = acc;
          }
          F1_INVERT(k0 + 16);
        } else {
          const int wtid = tid - 64;
          for (int o = wtid; o < 48 * rest; o += 448) {
            int rr = o / rest, c = o - rr * rest;
            int r = rr < k0 ? rr : rr + 16;
            bool excl = (r >= k0 + 16) && (r < k0 + 32) && (c < 16);
            if (!excl) {
              double acc = Mg[r][k0 + 16 + c];
#pragma unroll
              for (int t = 0; t < 16; ++t) acc -= Mg[r][k0 + t] * Pbuf[t][c];
              Mg[r][k0 + 16 + c] = acc;
            }
          }
          for (int o = wtid; o < 16 * rest; o += 448) {
            int t = o / rest, c = o - t * rest;
            Mg[k0 + t][k0 + 16 + c] = Pbuf[t][c];
          }
        }
      } else {
        // last panel: rest=2, tiny — all threads
        for (int o = tid; o < 48 * rest; o += NT) {
          int rr = o / rest, c = o - rr * rest;
          int r = rr < k0 ? rr : rr + 16;
          double acc = Mg[r][k0 + 16 + c];
#pragma unroll
          for (int t = 0; t < 16; ++t) acc -= Mg[r][k0 + t] * Pbuf[t][c];
          Mg[r][k0 + 16 + c] = acc;
        }
        for (int o = tid; o < 16 * rest; o += NT) {
          int t = o / rest, c = o - t * rest;
          Mg[k0 + t][k0 + 16 + c] = Pbuf[t][c];
        }
      }
      __syncthreads();
    }

    // ---- Phase H: fairness border solve (redundant in every wave) --------
    double ddl, tf;
    {
      double qsum = 0.0, fg = 0.0, fzs = 0.0;
#pragma unroll
      for (int q = 0; q < NW; ++q) { qsum += wpQ[q]; fg += wpFg[q]; fzs += wpFz[q]; }
      double h1 = Mg[lane][64], h2 = Mg[lane][65];
      double a1 = wsum(usv[lane] * usv[lane]);
      double a2 = wsum(usv[lane] * rsv[lane]);
      double a3 = wsum(mw0[lane] * h1);
      double a4 = wsum(mw0[lane] * h2);
      double qp  = qsum + SREG - a1;
      double r3p = (fg + fzs) - a2;
      tf  = (r3p - a3) / (qp - a4);
      ddl = h1 - tf * h2;
    }

    // ---- Phase I: recompute Newton pieces, dz->LDS, alpha search ---------
    double bs = 0.0;          // s-side rate max
    double rl = BIGV;         // lambda-side ratio min
#pragma unroll
    for (int k = 0; k < NCH; ++k) {
      int i = w + NW * k;
      double fek = fvec[i] * ev;
      double is1 = 1.0 / s1[k], is2 = 1.0 / s2[k];
      double D = 1.0 / (EPSQ + l1[k] * is1 + l2[k] * is2);
      double rd  = EPSQ * z[k] + p[k] + (yav[i] + ydv[lane] + yt * fek) + (l2[k] - l1[k]);
      double tt1 = (mu01 - l1[k] * z[k]) * is1;
      double tt2 = (l2[k] * (z[k] - 1.0) + mu01) * is2;
      double rz  = -(rd - tt1 + tt2);
      double rdot = wsum(D * ddl);
      double dv = (rhs1[i] - rdot - uvv[i] * tf) / Rhv[i];
      if (lane == 0) dav[i] = dv;
      double d   = (rz - (dv + ddl + tf * fek)) * D;
      dzS[k][tid] = d;
      double ds1 = d - (s1[k] - z[k]);
      double ds2 = -(z[k] + s2[k] - 1.0) - d;
      bs = fmax(bs, fmax(-ds1 * is1, -ds2 * is2));
      double dl1 = (-(l1[k] * s1[k] - mu01) - l1[k] * ds1) * is1;
      double dl2 = (-(l2[k] * s2[k] - mu01) - l2[k] * ds2) * is2;
      if (dl1 < 0.0) rl = fmin(rl, -l1[k] / dl1);
      if (dl2 < 0.0) rl = fmin(rl, -l2[k] / dl2);
    }
    bs = wmax(bs);
    rl = wmin(rl);
    if (lane == 0) { wpS[w] = bs; wpL[w] = rl; }
    __syncthreads();
    double al;
    {
      double bm = wpS[0], rm = wpL[0];
#pragma unroll
      for (int q = 1; q < NW; ++q) { bm = fmax(bm, wpS[q]); rm = fmin(rm, wpL[q]); }
      double a_s = bm > 0.0 ? 1.0 / bm : BIGV;
      al = fmin(1.0, 0.99 * fmin(a_s, rm));
    }

    // ---- update (dz from LDS; no yav/ydv reads -> race-free) -------------
#pragma unroll
    for (int k = 0; k < NCH; ++k) {
      int i = w + NW * k;
      double is1 = 1.0 / s1[k], is2 = 1.0 / s2[k];
      double d   = dzS[k][tid];
      double ds1 = d - (s1[k] - z[k]);
      double ds2 = -(z[k] + s2[k] - 1.0) - d;
      double dl1 = (-(l1[k] * s1[k] - mu01) - l1[k] * ds1) * is1;
      double dl2 = (-(l2[k] * s2[k] - mu01) - l2[k] * ds2) * is2;
      z[k]  += al * d;
      s1[k] += al * ds1;
      s2[k] += al * ds2;
      l1[k] += al * dl1;
      l2[k] += al * dl2;
      if (lane == 0) yav[i] += al * dav[i];
    }
    if (tid < 64) ydv[tid] += al * ddl;
    if (tid == 0) scal[6] += al * tf;
    // no end barrier: Phase A's barrier orders these LDS writes before C's reads
  }

  // ---- output (fp32) ------------------------------------------------------
#pragma unroll
  for (int k = 0; k < NCH; ++k) {
    int e = tid + NT * k;
    outp[(size_t)b * NXX + e] = (float)z[k];
  }
}

extern "C" void kernel_launch(void* const* d_in, const int* in_sizes, int n_in,
                              void* d_out, int out_size, void* d_ws, size_t ws_size,
                              hipStream_t stream)
{
  const float* x   = (const float*)d_in[0];
  const float* gid = (const float*)d_in[1];
  const float* ex  = (const float*)d_in[2];
  float* out = (float*)d_out;
  int nb = in_sizes[0] / NXX;   // 32 batches
  hipLaunchKernelGGL(ipm_kernel, dim3(nb), dim3(NT), 0, stream, x, gid, ex, out);
}

// Round 13
// 1243.512 us; speedup vs baseline: 1.4877x; 1.1023x over previous
//
#include <hip/hip_runtime.h>
#include <math.h>

#define NN    64
#define NXX   4096
#define NT    512
#define NW    8          // waves per block
#define NCH   8          // elements per thread = NXX/NT
#define NITER 25
#define EPSQ  0.1
#define SREG  1e-9

// ---- wave (64-lane) reductions -------------------------------------------
__device__ __forceinline__ double wsum(double v) {
#pragma unroll
  for (int m = 32; m > 0; m >>= 1) v += __shfl_xor(v, m, 64);
  return v;
}
__device__ __forceinline__ double wmax(double v) {
#pragma unroll
  for (int m = 32; m > 0; m >>= 1) v = fmax(v, __shfl_xor(v, m, 64));
  return v;
}
// reciprocal via v_rcp_f64 + 2 Newton steps (~1 ulp; tolerance is 2e-2)
__device__ __forceinline__ double rcpNR(double x) {
  double r = __builtin_amdgcn_rcp(x);
  r = r * (2.0 - x * r);
  r = r * (2.0 - x * r);
  return r;
}

// 16x16 pivot-block inversion in one wave (registers + shfl), rcp+2NR divide.
#define F1_INVERT(K0)                                                         \
  {                                                                           \
    const int r_ = lane >> 2, q_ = lane & 3;                                  \
    double Brow[4];                                                           \
    _Pragma("unroll")                                                         \
    for (int e = 0; e < 4; ++e) Brow[e] = Mg[(K0) + r_][(K0) + ((e << 2) | q_)]; \
    _Pragma("unroll")                                                         \
    for (int t = 0; t < 16; ++t) {                                            \
      const int et = t >> 2, qt = t & 3;                                      \
      double pm  = __shfl(Brow[et], (r_ << 2) | qt, 64);                      \
      double pv  = __shfl(Brow[et], (t << 2) | qt, 64);                       \
      double pr0 = __shfl(Brow[0], (t << 2) | q_, 64);                        \
      double pr1 = __shfl(Brow[1], (t << 2) | q_, 64);                        \
      double pr2 = __shfl(Brow[2], (t << 2) | q_, 64);                        \
      double pr3 = __shfl(Brow[3], (t << 2) | q_, 64);                        \
      double ip = __builtin_amdgcn_rcp(pv);                                   \
      ip = ip * (2.0 - pv * ip);                                              \
      ip = ip * (2.0 - pv * ip);                                              \
      double ps0 = pr0 * ip, ps1 = pr1 * ip, ps2 = pr2 * ip, ps3 = pr3 * ip;  \
      if (r_ == t) {                                                          \
        Brow[0] = ps0; Brow[1] = ps1; Brow[2] = ps2; Brow[3] = ps3;           \
        if (q_ == qt) Brow[et] = ip;                                          \
      } else {                                                                \
        Brow[0] -= pm * ps0; Brow[1] -= pm * ps1;                             \
        Brow[2] -= pm * ps2; Brow[3] -= pm * ps3;                             \
        if (q_ == qt) Brow[et] = -pm * ip;                                    \
      }                                                                       \
    }                                                                         \
    _Pragma("unroll")                                                         \
    for (int e = 0; e < 4; ++e) Binv[r_][(e << 2) | q_] = Brow[e];            \
  }

// One block per batch element. 512 threads = 8 waves = exactly 2 waves/EU
// (LDS caps at 1 block/CU). waves_per_eu(2,2) asks for the 256-VGPR budget.
__global__ __attribute__((amdgpu_flat_work_group_size(NT, NT),
                          amdgpu_waves_per_eu(2, 2)))
void ipm_kernel(const float* __restrict__ xin, const float* __restrict__ gidin,
                const float* __restrict__ expin, float* __restrict__ outp)
{
  const int b    = blockIdx.x;
  const int tid  = threadIdx.x;
  const int lane = tid & 63;
  const int w    = tid >> 6;     // wave id 0..7

  // ---- LDS ----------------------------------------------------------------
  __shared__ double DnT[64][65];     // DnT[j][i] = invD(i,j)/sqrt(Rh_i)
  __shared__ double Mg[64][67];      // augmented reduced Schur [M | rhs_d | mw]
  __shared__ double Pbuf[16][52];
  __shared__ double Binv[16][18];
  __shared__ double cpZ[NW][64], cpA[NW][64], cpB[NW][64], cpC[NW][64];
  __shared__ double rhs1[64], rhs2v[64];
  __shared__ double Rhv[64], Ruv[64], ccv[64], wvv[64], iRh[64];
  __shared__ double usv[64], rsv[64], uvv[64], mw0[64];
  __shared__ double yav[64], ydv[64];
  __shared__ double fvec[64], evec[64];
  __shared__ double wpFz[NW], wpMu[NW], wpQ[NW], wpFg[NW], wpS[NW];
  __shared__ double scal[8];  // 6=yt 7=gsum

  // ---- constants f, e; init y --------------------------------------------
  if (tid < 64) {
    fvec[tid] = (double)gidin[tid];   // reference uses group_ids[0] for ALL batches
    evec[tid] = (double)expin[tid];
    yav[tid] = 0.0; ydv[tid] = 0.0;
  }
  if (tid == 0) scal[6] = 0.0;
  __syncthreads();
  if (tid == 0) {
    double gs = 0.0;
    for (int i = 0; i < 64; ++i) gs += fvec[i];
    scal[7] = gs;
  }
  __syncthreads();
  if (tid < 64) {
    double g = fvec[tid], gs = scal[7];
    fvec[tid] = g / gs - (1.0 - g) / (64.0 - gs);
  }
  __syncthreads();

  // ---- per-thread state ---------------------------------------------------
  double p[NCH], z[NCH], s1[NCH], s2[NCH], l1[NCH], l2[NCH];
  const double ev = evec[lane];
#pragma unroll
  for (int k = 0; k < NCH; ++k) {
    p[k] = (double)xin[(size_t)b * NXX + tid + NT * k];
    z[k] = 0.0; s1[k] = 1.0; s2[k] = 1.0; l1[k] = 1.0; l2[k] = 1.0;
  }

  // ======================= main IPM loop ==================================
  for (int iter = 0; iter < NITER; ++iter) {
    // ---- Phase A: row sums of z, fairness/mu partials --------------------
    double rq1[NCH];
    double cz = 0.0, fz = 0.0, msl = 0.0;
#pragma unroll
    for (int k = 0; k < NCH; ++k) {
      int i = w + NW * k;
      double fek = fvec[i] * ev;
      rq1[k] = wsum(z[k]) - 1.0;
      cz  += z[k];
      fz  += fek * z[k];
      msl += s1[k] * l1[k] + s2[k] * l2[k];
    }
    cpZ[w][lane] = cz;
    {
      double a = wsum(fz), c = wsum(msl);
      if (lane == 0) { wpFz[w] = a; wpMu[w] = c; }
    }
    __syncthreads();

    // ---- Phase C: invD, rhs_z, first-order reductions, DnT write ---------
    double mu8 = 0.0;
#pragma unroll
    for (int q = 0; q < NW; ++q) mu8 += wpMu[q];
    const double mu01 = 0.1 * (mu8 / 8192.0);
    const double yt   = scal[6];
    double dinv[NCH], rz[NCH], is1[NCH], is2[NCH];
    double cD = 0.0, cfD = 0.0, cg = 0.0, qac = 0.0, fgac = 0.0;
#pragma unroll
    for (int k = 0; k < NCH; ++k) {
      int i = w + NW * k;
      double fek = fvec[i] * ev;
      double s12 = s1[k] * s2[k];
      double den = EPSQ * s12 + l1[k] * s2[k] + l2[k] * s1[k];
      double D   = s12 * rcpNR(den);
      double u   = rcpNR(s12);
      is1[k] = s2[k] * u;  is2[k] = s1[k] * u;
      dinv[k] = D;
      double rd  = EPSQ * z[k] + p[k] + (yav[i] + ydv[lane] + yt * fek) + (l2[k] - l1[k]);
      double tt1 = (mu01 - l1[k] * z[k]) * is1[k];
      double tt2 = (l2[k] * (z[k] - 1.0) + mu01) * is2[k];
      double r = -(rd - tt1 + tt2);
      rz[k] = r;
      double g = r * D;
      double sD  = wsum(D);
      double sED = wsum(ev * D);
      double sg  = wsum(g);
      double Rh  = sD + SREG;
      if (lane == 0) {
        Rhv[i]  = Rh;
        Ruv[i]  = sED;
        rhs1[i] = sg + rq1[k];
      }
      DnT[lane][i] = D * rsqrt(Rh);
      cD  += D;  cfD += fvec[i] * D;  cg += g;
      qac += fek * fek * D;
      fgac += fek * g;
    }
    cpA[w][lane] = cD; cpB[w][lane] = cfD; cpC[w][lane] = cg;
    {
      double a = wsum(qac), c = wsum(fgac);
      if (lane == 0) { wpQ[w] = a; wpFg[w] = c; }
    }
    __syncthreads();

    // ---- Phase D: column-sum finalize + border vectors -------------------
    if (tid < 64) {
      double sZ = 0.0, sA = 0.0, sB = 0.0, sC = 0.0;
#pragma unroll
      for (int q = 0; q < NW; ++q) {
        sZ += cpZ[q][tid]; sA += cpA[q][tid]; sB += cpB[q][tid]; sC += cpC[q][tid];
      }
      ccv[tid]   = sA;
      wvv[tid]   = evec[tid] * sB;
      rhs2v[tid] = sC + sZ - 1.0;
      double ir  = rsqrt(Rhv[tid]);
      iRh[tid]   = ir * ir;
      double u   = fvec[tid] * Ruv[tid];
      uvv[tid] = u;
      usv[tid] = u * ir;
      rsv[tid] = rhs1[tid] * ir;
    }
    __syncthreads();

    // ---- Phase E (+F1(0) fused): wave0 builds+inverts block 0; waves 1-7
    //      build remaining upper tiles with inline mirror + border columns --
    if (w == 0) {
      // full 16x16 block 0: lane -> row r=lane&15, col group (lane>>4)*4
      const int r   = lane & 15;
      const int c0b = (lane >> 4) << 2;
      double m0 = 0.0, m1 = 0.0, m2 = 0.0, m3 = 0.0;
#pragma unroll 4
      for (int i = 0; i < 64; ++i) {
        double av = DnT[r][i];
        m0 += av * DnT[c0b + 0][i];
        m1 += av * DnT[c0b + 1][i];
        m2 += av * DnT[c0b + 2][i];
        m3 += av * DnT[c0b + 3][i];
      }
      Mg[r][c0b + 0] = (r == c0b + 0 ? ccv[r] + SREG : 0.0) - m0;
      Mg[r][c0b + 1] = (r == c0b + 1 ? ccv[r] + SREG : 0.0) - m1;
      Mg[r][c0b + 2] = (r == c0b + 2 ? ccv[r] + SREG : 0.0) - m2;
      Mg[r][c0b + 3] = (r == c0b + 3 ? ccv[r] + SREG : 0.0) - m3;
      F1_INVERT(0);                 // wave-lockstep: sees own wave's writes
    } else {
      const int wtid = tid - 64;    // 0..447
      if (wtid < 272) {
        int R = 0;
#pragma unroll
        for (int r = 1; r < 16; ++r) if (wtid >= r * (33 - r)) R = r;
        const int C = 2 * R + (wtid - R * (33 - R));
        if (!(R <= 3 && C <= 7)) {  // skip block-0 tiles (wave0 owns them)
          const int r0 = R << 2, c0 = C << 1;
          double m00=0.0,m01=0.0,m10=0.0,m11=0.0,m20=0.0,m21=0.0,m30=0.0,m31=0.0;
#pragma unroll 4
          for (int i = 0; i < 64; ++i) {
            double a0 = DnT[r0+0][i], a1 = DnT[r0+1][i];
            double a2 = DnT[r0+2][i], a3 = DnT[r0+3][i];
            double b0v = DnT[c0+0][i], b1v = DnT[c0+1][i];
            m00 += a0*b0v; m01 += a0*b1v;
            m10 += a1*b0v; m11 += a1*b1v;
            m20 += a2*b0v; m21 += a2*b1v;
            m30 += a3*b0v; m31 += a3*b1v;
          }
          double v;
          v = ((r0+0)==(c0+0)?ccv[r0+0]+SREG:0.0)-m00; Mg[r0+0][c0+0]=v; if(r0+0<c0+0)Mg[c0+0][r0+0]=v;
          v = ((r0+0)==(c0+1)?ccv[r0+0]+SREG:0.0)-m01; Mg[r0+0][c0+1]=v; if(r0+0<c0+1)Mg[c0+1][r0+0]=v;
          v = ((r0+1)==(c0+0)?ccv[r0+1]+SREG:0.0)-m10; Mg[r0+1][c0+0]=v; if(r0+1<c0+0)Mg[c0+0][r0+1]=v;
          v = ((r0+1)==(c0+1)?ccv[r0+1]+SREG:0.0)-m11; Mg[r0+1][c0+1]=v; if(r0+1<c0+1)Mg[c0+1][r0+1]=v;
          v = ((r0+2)==(c0+0)?ccv[r0+2]+SREG:0.0)-m20; Mg[r0+2][c0+0]=v; if(r0+2<c0+0)Mg[c0+0][r0+2]=v;
          v = ((r0+2)==(c0+1)?ccv[r0+2]+SREG:0.0)-m21; Mg[r0+2][c0+1]=v; if(r0+2<c0+1)Mg[c0+1][r0+2]=v;
          v = ((r0+3)==(c0+0)?ccv[r0+3]+SREG:0.0)-m30; Mg[r0+3][c0+0]=v; if(r0+3<c0+0)Mg[c0+0][r0+3]=v;
          v = ((r0+3)==(c0+1)?ccv[r0+3]+SREG:0.0)-m31; Mg[r0+3][c0+1]=v; if(r0+3<c0+1)Mg[c0+1][r0+3]=v;
        }
      } else if (wtid < 400) {
        // border columns 64 (rhs_d) / 65 (mw): 128 serial dots of length 64
        const int d = wtid - 272;
        const int j = d & 63, cc = d >> 6;
        double acc = 0.0;
#pragma unroll 8
        for (int i = 0; i < 64; ++i) {
          double vv = cc ? usv[i] : rsv[i];
          acc += DnT[j][i] * vv;
        }
        if (cc == 0) Mg[j][64] = rhs2v[j] - acc;
        else { double vv2 = wvv[j] - acc; Mg[j][65] = vv2; mw0[j] = vv2; }
      }
    }
    __syncthreads();

    // ---- Phase F: block Gauss-Jordan, 4 panels; F1(next) hidden in F3 ----
#pragma unroll
    for (int pk = 0; pk < 4; ++pk) {
      const int k0   = 16 * pk;
      const int rest = 50 - k0;        // 50, 34, 18, 2

      // -- F2: Pbuf = Binv * Mg[panel rows, rest cols] --------------------
      for (int o = tid; o < 16 * rest; o += NT) {
        int t = o / rest, c = o - t * rest;
        double acc = 0.0;
#pragma unroll
        for (int s = 0; s < 16; ++s) acc += Binv[t][s] * Mg[k0 + s][k0 + 16 + c];
        Pbuf[t][c] = acc;
      }
      __syncthreads();

      // -- F3 phase -------------------------------------------------------
      if (pk < 3) {
        if (w == 0) {
          // update next pivot block (16x16), then invert it
#pragma unroll
          for (int e = 0; e < 4; ++e) {
            int idx = lane + 64 * e;                 // 0..255
            int r = k0 + 16 + (idx >> 4), c = (idx & 15);
            double acc = Mg[r][k0 + 16 + c];
#pragma unroll
            for (int t = 0; t < 16; ++t) acc -= Mg[r][k0 + t] * Pbuf[t][c];
            Mg[r][k0 + 16 + c] = acc;
          }
          F1_INVERT(k0 + 16);
        } else {
          const int wtid = tid - 64;
          for (int o = wtid; o < 48 * rest; o += 448) {
            int rr = o / rest, c = o - rr * rest;
            int r = rr < k0 ? rr : rr + 16;
            bool excl = (r >= k0 + 16) && (r < k0 + 32) && (c < 16);
            if (!excl) {
              double acc = Mg[r][k0 + 16 + c];
#pragma unroll
              for (int t = 0; t < 16; ++t) acc -= Mg[r][k0 + t] * Pbuf[t][c];
              Mg[r][k0 + 16 + c] = acc;
            }
          }
          for (int o = wtid; o < 16 * rest; o += 448) {
            int t = o / rest, c = o - t * rest;
            Mg[k0 + t][k0 + 16 + c] = Pbuf[t][c];
          }
        }
      } else {
        // last panel: rest=2, tiny — all threads
        for (int o = tid; o < 48 * rest; o += NT) {
          int rr = o / rest, c = o - rr * rest;
          int r = rr < k0 ? rr : rr + 16;
          double acc = Mg[r][k0 + 16 + c];
#pragma unroll
          for (int t = 0; t < 16; ++t) acc -= Mg[r][k0 + t] * Pbuf[t][c];
          Mg[r][k0 + 16 + c] = acc;
        }
        for (int o = tid; o < 16 * rest; o += NT) {
          int t = o / rest, c = o - t * rest;
          Mg[k0 + t][k0 + 16 + c] = Pbuf[t][c];
        }
      }
      __syncthreads();
    }

    // ---- Phase H: fairness border solve (redundant in every wave) --------
    double ddl, tf;
    {
      double qsum = 0.0, fg = 0.0, fzs = 0.0;
#pragma unroll
      for (int q = 0; q < NW; ++q) { qsum += wpQ[q]; fg += wpFg[q]; fzs += wpFz[q]; }
      double h1 = Mg[lane][64], h2 = Mg[lane][65];
      double a1 = wsum(usv[lane] * usv[lane]);
      double a2 = wsum(usv[lane] * rsv[lane]);
      double a3 = wsum(mw0[lane] * h1);
      double a4 = wsum(mw0[lane] * h2);
      double qp  = qsum + SREG - a1;
      double r3p = (fg + fzs) - a2;
      tf  = (r3p - a3) / (qp - a4);
      ddl = h1 - tf * h2;
    }

    // ---- Phase I: row duals (registers), rate-based alpha (branchless) ---
    double dar[NCH];
    double bmax = 0.0;
#pragma unroll
    for (int k = 0; k < NCH; ++k) {
      int i = w + NW * k;
      double fek = fvec[i] * ev;
      double rdot = wsum(dinv[k] * ddl);
      double dv = (rhs1[i] - rdot - uvv[i] * tf) * iRh[i];
      dar[k] = dv;
      double d   = (rz[k] - (dv + ddl + tf * fek)) * dinv[k];
      double ds1 = d - (s1[k] - z[k]);
      double ds2 = -(z[k] + s2[k] - 1.0) - d;
      bmax = fmax(bmax, fmax(-ds1 * is1[k], -ds2 * is2[k]));
      double dl1 = (-(l1[k] * s1[k] - mu01) - l1[k] * ds1) * is1[k];
      double dl2 = (-(l2[k] * s2[k] - mu01) - l2[k] * ds2) * is2[k];
      bmax = fmax(bmax, fmax(-dl1 * rcpNR(l1[k]), -dl2 * rcpNR(l2[k])));
    }
    bmax = wmax(bmax);
    if (lane == 0) wpS[w] = bmax;
    __syncthreads();
    double al;
    {
      double bm = wpS[0];
#pragma unroll
      for (int q = 1; q < NW; ++q) bm = fmax(bm, wpS[q]);
      al = fmin(1.0, 0.99 * rcpNR(fmax(bm, 1e-30)));
    }

    // ---- update ----------------------------------------------------------
#pragma unroll
    for (int k = 0; k < NCH; ++k) {
      int i = w + NW * k;
      double fek = fvec[i] * ev;
      double d   = (rz[k] - (dar[k] + ddl + tf * fek)) * dinv[k];
      double ds1 = d - (s1[k] - z[k]);
      double ds2 = -(z[k] + s2[k] - 1.0) - d;
      double dl1 = (-(l1[k] * s1[k] - mu01) - l1[k] * ds1) * is1[k];
      double dl2 = (-(l2[k] * s2[k] - mu01) - l2[k] * ds2) * is2[k];
      z[k]  += al * d;
      s1[k] += al * ds1;
      s2[k] += al * ds2;
      l1[k] += al * dl1;
      l2[k] += al * dl2;
      if (lane == 0) yav[i] += al * dar[k];
    }
    if (tid < 64) ydv[tid] += al * ddl;
    if (tid == 0) scal[6] += al * tf;
    // no end barrier: Phase A's barrier orders these LDS writes before C's reads
  }

  // ---- output (fp32) ------------------------------------------------------
#pragma unroll
  for (int k = 0; k < NCH; ++k) {
    int e = tid + NT * k;
    outp[(size_t)b * NXX + e] = (float)z[k];
  }
}

extern "C" void kernel_launch(void* const* d_in, const int* in_sizes, int n_in,
                              void* d_out, int out_size, void* d_ws, size_t ws_size,
                              hipStream_t stream)
{
  const float* x   = (const float*)d_in[0];
  const float* gid = (const float*)d_in[1];
  const float* ex  = (const float*)d_in[2];
  float* out = (float*)d_out;
  int nb = in_sizes[0] / NXX;   // 32 batches
  hipLaunchKernelGGL(ipm_kernel, dim3(nb), dim3(NT), 0, stream, x, gid, ex, out);
}